// Round 1
// baseline (3297.416 us; speedup 1.0000x reference)
//
#include <hip/hip_runtime.h>
#include <math.h>

#define DATA 64
#define WIDTH 256
#define BATCHN 512
#define TPTS 16
#define MAXSUB 8

#define RTOLc 1e-3f
#define ATOLc 1e-6f
#define SAFETYc 0.9f
#define FMINc 0.2f
#define FMAXc 10.0f

// Tsit5 tableau (f32 literals == f32(np double literals))
#define A21 0.161f
#define A31 (-0.008480655492356989f)
#define A32 0.335480655492357f
#define A41 2.8971530571054935f
#define A42 (-6.359448489975075f)
#define A43 4.3622954328695815f
#define A51 5.325864828439257f
#define A52 (-11.748883564062828f)
#define A53 7.4955393428898365f
#define A54 (-0.09249506636175525f)
#define A61 5.86145544294642f
#define A62 (-12.92096931784711f)
#define A63 8.159367898576159f
#define A64 (-0.071584973281401f)
#define A65 (-0.028269050394068383f)
#define B1c 0.09646076681806523f
#define B2c 0.01f
#define B3c 0.4798896504144996f
#define B4c 1.379008574103742f
#define B5c (-3.290069515436081f)
#define B6c 2.324710524099774f
#define E1c (-0.001780011052226f)
#define E2c (-0.000816434459657f)
#define E3c 0.007880878010262f
#define E4c (-0.144711007173263f)
#define E5c 0.582357165452555f
#define E6c (-0.458082105929187f)
#define E7c 0.015151515151515152f

__device__ __forceinline__ float softplus_jax(float x) {
    // jax.nn.softplus(x) == logaddexp(x, 0) == max(x,0) + log1p(exp(-|x|))
    return fmaxf(x, 0.0f) + log1pf(expf(-fabsf(x)));
}

// Weight accessors: TW=true -> transposed layout in ws (k-major, coalesced by
// output index); TW=false -> original row-major layout (fallback if ws_size
// is too small for the transposed copies).
template <bool TW>
__device__ __forceinline__ float ldw0(const float* __restrict__ W, int k, int r) {
    return TW ? W[k * WIDTH + r] : W[r * DATA + k];
}
template <bool TW>
__device__ __forceinline__ float ldw1(const float* __restrict__ W, int k, int r) {
    return TW ? W[k * WIDTH + r] : W[r * WIDTH + k];
}
template <bool TW>
__device__ __forceinline__ float ldw2(const float* __restrict__ W, int k, int d) {
    return TW ? W[k * DATA + d] : W[d * WIDTH + k];
}

// One MLP evaluation: kout = W2 @ softplus(W1 @ softplus(W0 @ yin + b0) + b1) + b2
// yin, kout are LDS pointers (DATA floats). Caller must have synced so yin is
// visible. Ends with a __syncthreads() so kout is visible to all.
template <bool TW>
__device__ __forceinline__ void feval(
    const float* __restrict__ yin, float* __restrict__ kout,
    const float* __restrict__ W0p, const float* __restrict__ W1p,
    const float* __restrict__ W2p,
    const float* __restrict__ sb0, const float* __restrict__ sb1,
    const float* __restrict__ sb2,
    float* __restrict__ sh0, float* __restrict__ sh1,
    float* __restrict__ spsum, int t)
{
    // ---- layer 0: 256 rows, 64-deep dot. thread t = row. 2 acc chains.
    {
        float a0 = 0.0f, a1 = 0.0f;
#pragma unroll
        for (int kk = 0; kk < 32; ++kk) {
            a0 = fmaf(ldw0<TW>(W0p, kk, t),      yin[kk],      a0);
            a1 = fmaf(ldw0<TW>(W0p, 32 + kk, t), yin[32 + kk], a1);
        }
        sh0[t] = softplus_jax(a0 + a1 + sb0[t]);
    }
    __syncthreads();
    // ---- layer 1: 256 rows, 256-deep dot. thread t = row. 4 acc chains.
    {
        float a0 = 0.0f, a1 = 0.0f, a2 = 0.0f, a3 = 0.0f;
#pragma unroll 16
        for (int kk = 0; kk < 64; ++kk) {
            a0 = fmaf(ldw1<TW>(W1p, kk, t),       sh0[kk],       a0);
            a1 = fmaf(ldw1<TW>(W1p, 64 + kk, t),  sh0[64 + kk],  a1);
            a2 = fmaf(ldw1<TW>(W1p, 128 + kk, t), sh0[128 + kk], a2);
            a3 = fmaf(ldw1<TW>(W1p, 192 + kk, t), sh0[192 + kk], a3);
        }
        sh1[t] = softplus_jax((a0 + a1) + (a2 + a3) + sb1[t]);
    }
    __syncthreads();
    // ---- layer 2: 64 rows, 256-deep dot. 4-way split-k across the block:
    // d = t & 63 (row), c = t >> 6 (k-chunk). Coalesced in transposed layout.
    {
        const int d = t & (DATA - 1);
        const int c = t >> 6;
        const int kbase = c * 64;
        float a0 = 0.0f, a1 = 0.0f;
#pragma unroll
        for (int kk = 0; kk < 32; ++kk) {
            a0 = fmaf(ldw2<TW>(W2p, kbase + kk, d),      sh1[kbase + kk],      a0);
            a1 = fmaf(ldw2<TW>(W2p, kbase + 32 + kk, d), sh1[kbase + 32 + kk], a1);
        }
        spsum[t] = a0 + a1;
    }
    __syncthreads();
    if (t < DATA) {
        kout[t] = ((spsum[t] + spsum[t + 64]) + (spsum[t + 128] + spsum[t + 192])) + sb2[t];
    }
    __syncthreads();
}

template <bool TW>
__global__ __launch_bounds__(256)
void ode_kernel(const float* __restrict__ ts, const float* __restrict__ y0,
                const float* __restrict__ b0, const float* __restrict__ b1,
                const float* __restrict__ b2,
                const float* __restrict__ W0p, const float* __restrict__ W1p,
                const float* __restrict__ W2p,
                float* __restrict__ out)
{
    __shared__ float s_y[DATA], s_yst[DATA], s_ynew[DATA];
    __shared__ float s_k[7][DATA];
    __shared__ float s_h0[WIDTH], s_h1[WIDTH];
    __shared__ float s_psum[WIDTH];
    __shared__ float s_b0[WIDTH], s_b1[WIDTH], s_b2[DATA];
    __shared__ float s_red;

    const int b = blockIdx.x;
    const int t = threadIdx.x;

    // preload biases; load y0; emit output row 0
    s_b0[t] = b0[t];
    s_b1[t] = b1[t];
    if (t < DATA) {
        s_b2[t] = b2[t];
        float v = y0[b * DATA + t];
        s_y[t] = v;
        out[(size_t)b * TPTS * DATA + t] = v;
    }
    __syncthreads();

    float dt = ts[1] - ts[0];

    for (int iv = 0; iv < TPTS - 1; ++iv) {
        const float t1v = ts[iv + 1];
        float tc = ts[iv];

        for (int ss = 0; ss < MAXSUB; ++ss) {
            const float rem = t1v - tc;
            if (rem <= 1e-6f) break;  // exact identity iterations in the reference
            const float dt_c = fminf(dt, rem);

            // stage 1: k1 = f(y)
            feval<TW>(s_y, s_k[0], W0p, W1p, W2p, s_b0, s_b1, s_b2, s_h0, s_h1, s_psum, t);
            // stage 2
            if (t < DATA) s_yst[t] = s_y[t] + dt_c * (A21 * s_k[0][t]);
            __syncthreads();
            feval<TW>(s_yst, s_k[1], W0p, W1p, W2p, s_b0, s_b1, s_b2, s_h0, s_h1, s_psum, t);
            // stage 3
            if (t < DATA) s_yst[t] = s_y[t] + dt_c * (A31 * s_k[0][t] + A32 * s_k[1][t]);
            __syncthreads();
            feval<TW>(s_yst, s_k[2], W0p, W1p, W2p, s_b0, s_b1, s_b2, s_h0, s_h1, s_psum, t);
            // stage 4
            if (t < DATA) s_yst[t] = s_y[t] + dt_c * (A41 * s_k[0][t] + A42 * s_k[1][t] + A43 * s_k[2][t]);
            __syncthreads();
            feval<TW>(s_yst, s_k[3], W0p, W1p, W2p, s_b0, s_b1, s_b2, s_h0, s_h1, s_psum, t);
            // stage 5
            if (t < DATA) s_yst[t] = s_y[t] + dt_c * (A51 * s_k[0][t] + A52 * s_k[1][t] + A53 * s_k[2][t] + A54 * s_k[3][t]);
            __syncthreads();
            feval<TW>(s_yst, s_k[4], W0p, W1p, W2p, s_b0, s_b1, s_b2, s_h0, s_h1, s_psum, t);
            // stage 6
            if (t < DATA) s_yst[t] = s_y[t] + dt_c * (A61 * s_k[0][t] + A62 * s_k[1][t] + A63 * s_k[2][t] + A64 * s_k[3][t] + A65 * s_k[4][t]);
            __syncthreads();
            feval<TW>(s_yst, s_k[5], W0p, W1p, W2p, s_b0, s_b1, s_b2, s_h0, s_h1, s_psum, t);
            // y_new
            if (t < DATA) {
                s_ynew[t] = s_y[t] + dt_c * (B1c * s_k[0][t] + B2c * s_k[1][t] + B3c * s_k[2][t]
                                           + B4c * s_k[3][t] + B5c * s_k[4][t] + B6c * s_k[5][t]);
            }
            __syncthreads();
            // stage 7 (FSAL slot, only feeds the error estimate)
            feval<TW>(s_ynew, s_k[6], W0p, W1p, W2p, s_b0, s_b1, s_b2, s_h0, s_h1, s_psum, t);

            // embedded error estimate + I-controller
            if (t < DATA) {
                float e = dt_c * (E1c * s_k[0][t] + E2c * s_k[1][t] + E3c * s_k[2][t]
                                + E4c * s_k[3][t] + E5c * s_k[4][t] + E6c * s_k[5][t]
                                + E7c * s_k[6][t]);
                float sc = ATOLc + RTOLc * fmaxf(fabsf(s_y[t]), fabsf(s_ynew[t]));
                float r = e / sc;
                float v = r * r;
                // wave-64 butterfly reduce (threads 0..63 are exactly wave 0)
                for (int off = 32; off > 0; off >>= 1) v += __shfl_xor(v, off, 64);
                if (t == 0) s_red = v;
            }
            __syncthreads();
            const float err_norm = sqrtf(s_red * (1.0f / DATA));
            const bool accept = (err_norm <= 1.0f);
            float factor = SAFETYc * powf(fmaxf(err_norm, 1e-10f), -0.2f);
            factor = fminf(fmaxf(factor, FMINc), FMAXc);
            if (accept) {
                tc = tc + dt_c;
                if (t < DATA) s_y[t] = s_ynew[t];
            }
            dt = dt_c * factor;
            __syncthreads();
        }

        if (t < DATA) out[(size_t)b * TPTS * DATA + (size_t)(iv + 1) * DATA + t] = s_y[t];
    }
}

// Transpose weights into ws: WT0[k*256+r], WT1[k*256+r], WT2[k*64+d]
__global__ void prep_kernel(const float* __restrict__ W0, const float* __restrict__ W1,
                            const float* __restrict__ W2, float* __restrict__ ws)
{
    const int i = blockIdx.x * blockDim.x + threadIdx.x;
    const int N0 = WIDTH * DATA;           // 16384
    const int N1 = WIDTH * WIDTH;          // 65536
    const int N2 = DATA * WIDTH;           // 16384
    if (i < N0) {
        int k = i / WIDTH, r = i % WIDTH;
        ws[i] = W0[r * DATA + k];
    } else if (i < N0 + N1) {
        int j = i - N0;
        int k = j / WIDTH, r = j % WIDTH;
        ws[i] = W1[r * WIDTH + k];
    } else if (i < N0 + N1 + N2) {
        int j = i - (N0 + N1);
        int k = j / DATA, d = j % DATA;
        ws[i] = W2[d * WIDTH + k];
    }
}

extern "C" void kernel_launch(void* const* d_in, const int* in_sizes, int n_in,
                              void* d_out, int out_size, void* d_ws, size_t ws_size,
                              hipStream_t stream)
{
    const float* ts = (const float*)d_in[0];
    const float* y0 = (const float*)d_in[1];
    const float* W0 = (const float*)d_in[2];
    const float* b0 = (const float*)d_in[3];
    const float* W1 = (const float*)d_in[4];
    const float* b1 = (const float*)d_in[5];
    const float* W2 = (const float*)d_in[6];
    const float* b2 = (const float*)d_in[7];
    float* out = (float*)d_out;

    const size_t need = (size_t)(WIDTH * DATA + WIDTH * WIDTH + DATA * WIDTH) * sizeof(float);
    if (ws_size >= need) {
        float* ws = (float*)d_ws;
        const int total = WIDTH * DATA + WIDTH * WIDTH + DATA * WIDTH;
        prep_kernel<<<(total + 255) / 256, 256, 0, stream>>>(W0, W1, W2, ws);
        const float* WT0 = ws;
        const float* WT1 = ws + WIDTH * DATA;
        const float* WT2 = ws + WIDTH * DATA + WIDTH * WIDTH;
        ode_kernel<true><<<BATCHN, 256, 0, stream>>>(ts, y0, b0, b1, b2, WT0, WT1, WT2, out);
    } else {
        ode_kernel<false><<<BATCHN, 256, 0, stream>>>(ts, y0, b0, b1, b2, W0, W1, W2, out);
    }
}

// Round 2
// 444.247 us; speedup vs baseline: 7.4225x; 7.4225x over previous
//
#include <hip/hip_runtime.h>
#include <math.h>

#define DATA 64
#define WIDTH 256
#define BATCHN 512
#define TPTS 16
#define MAXSUB 8
#define NSAMP 2
#define NBLK (BATCHN / NSAMP)
#define NTHR 512

#define RTOLc 1e-3f
#define ATOLc 1e-6f
#define SAFETYc 0.9f
#define FMINc 0.2f
#define FMAXc 10.0f

// Tsit5 tableau
#define A21 0.161f
#define A31 (-0.008480655492356989f)
#define A32 0.335480655492357f
#define A41 2.8971530571054935f
#define A42 (-6.359448489975075f)
#define A43 4.3622954328695815f
#define A51 5.325864828439257f
#define A52 (-11.748883564062828f)
#define A53 7.4955393428898365f
#define A54 (-0.09249506636175525f)
#define A61 5.86145544294642f
#define A62 (-12.92096931784711f)
#define A63 8.159367898576159f
#define A64 (-0.071584973281401f)
#define A65 (-0.028269050394068383f)
#define B1c 0.09646076681806523f
#define B2c 0.01f
#define B3c 0.4798896504144996f
#define B4c 1.379008574103742f
#define B5c (-3.290069515436081f)
#define B6c 2.324710524099774f
#define E1c (-0.001780011052226f)
#define E2c (-0.000816434459657f)
#define E3c 0.007880878010262f
#define E4c (-0.144711007173263f)
#define E5c 0.582357165452555f
#define E6c (-0.458082105929187f)
#define E7c 0.015151515151515152f

__device__ __forceinline__ float softplus_jax(float x) {
    // jax.nn.softplus(x) == max(x,0) + log1p(exp(-|x|))
    return fmaxf(x, 0.0f) + log1pf(expf(-fabsf(x)));
}

#define DOT4(acc, wq, xv)                                                     \
    acc = fmaf((wq).x, (xv).x, acc); acc = fmaf((wq).y, (xv).y, acc);         \
    acc = fmaf((wq).z, (xv).z, acc); acc = fmaf((wq).w, (xv).w, acc);

// One MLP eval for BOTH samples. Inputs PIN0/PIN1 are 64-float LDS vectors.
// Leaves per-(sample,kc) partials in s_ps2; caller's epilogue combines.
// Thread roles: (r = t&255, h = t>>8) for layers 0/1; (d = t&63, kc = t>>6)
// for layer 2. Weights: w0q/w1q in VGPRs (k-range [h*32,+32) / [h*128,+128)),
// W2 transposed in LDS.
#define FEVAL_CORE(PIN0, PIN1)                                                \
    {   /* layer 0: 2-way split-k, register weights, broadcast inputs */      \
        const float4* xx0 = reinterpret_cast<const float4*>((PIN0) + h * 32); \
        const float4* xx1 = reinterpret_cast<const float4*>((PIN1) + h * 32); \
        float a0 = 0.f, a1 = 0.f, c0 = 0.f, c1 = 0.f;                         \
        _Pragma("unroll")                                                     \
        for (int j = 0; j < 8; j += 2) {                                      \
            float4 u = xx0[j], v = xx1[j];                                    \
            DOT4(a0, w0q[j], u); DOT4(a1, w0q[j], v);                         \
            float4 u2 = xx0[j + 1], v2 = xx1[j + 1];                          \
            DOT4(c0, w0q[j + 1], u2); DOT4(c1, w0q[j + 1], v2);               \
        }                                                                     \
        s_ps0[0][h][r] = a0 + c0;                                             \
        s_ps0[1][h][r] = a1 + c1;                                             \
    }                                                                         \
    __syncthreads();                                                          \
    /* h0 combine: thread (sample = h, row = r) */                            \
    s_h0[h][r] = softplus_jax(s_ps0[h][0][r] + s_ps0[h][1][r] + s_b0[r]);     \
    __syncthreads();                                                          \
    {   /* layer 1: 2-way split-k, register weights */                        \
        const float4* xx0 = reinterpret_cast<const float4*>(&s_h0[0][h * 128]); \
        const float4* xx1 = reinterpret_cast<const float4*>(&s_h0[1][h * 128]); \
        float a0 = 0.f, a1 = 0.f, c0 = 0.f, c1 = 0.f;                         \
        _Pragma("unroll")                                                     \
        for (int j = 0; j < 32; j += 2) {                                     \
            float4 u = xx0[j], v = xx1[j];                                    \
            DOT4(a0, w1q[j], u); DOT4(a1, w1q[j], v);                         \
            float4 u2 = xx0[j + 1], v2 = xx1[j + 1];                          \
            DOT4(c0, w1q[j + 1], u2); DOT4(c1, w1q[j + 1], v2);               \
        }                                                                     \
        s_ps1[0][h][r] = a0 + c0;                                             \
        s_ps1[1][h][r] = a1 + c1;                                             \
    }                                                                         \
    __syncthreads();                                                          \
    s_h1[h][r] = softplus_jax(s_ps1[h][0][r] + s_ps1[h][1][r] + s_b1[r]);     \
    __syncthreads();                                                          \
    {   /* layer 2: 8-way split-k, W2 from LDS (lane-consecutive, no conflicts) */ \
        const float4* xx0 = reinterpret_cast<const float4*>(&s_h1[0][kc * 32]); \
        const float4* xx1 = reinterpret_cast<const float4*>(&s_h1[1][kc * 32]); \
        float a0 = 0.f, a1 = 0.f;                                             \
        _Pragma("unroll")                                                     \
        for (int j = 0; j < 8; ++j) {                                         \
            float4 u = xx0[j], v = xx1[j];                                    \
            const int kb = kc * 32 + j * 4;                                   \
            float wa = sW2T[kb + 0][d], wb = sW2T[kb + 1][d];                 \
            float wc = sW2T[kb + 2][d], wd = sW2T[kb + 3][d];                 \
            a0 = fmaf(wa, u.x, a0); a1 = fmaf(wa, v.x, a1);                   \
            a0 = fmaf(wb, u.y, a0); a1 = fmaf(wb, v.y, a1);                   \
            a0 = fmaf(wc, u.z, a0); a1 = fmaf(wc, v.z, a1);                   \
            a0 = fmaf(wd, u.w, a0); a1 = fmaf(wd, v.w, a1);                   \
        }                                                                     \
        s_ps2[0][kc][d] = a0;                                                 \
        s_ps2[1][kc][d] = a1;                                                 \
    }                                                                         \
    __syncthreads();

#define KV_SUM(s)                                                             \
    (((s_ps2[s][0][d] + s_ps2[s][1][d]) + (s_ps2[s][2][d] + s_ps2[s][3][d]))  \
   + ((s_ps2[s][4][d] + s_ps2[s][5][d]) + (s_ps2[s][6][d] + s_ps2[s][7][d]))  \
   + s_b2[d])

__global__ __launch_bounds__(NTHR, 2)
void ode_kernel(const float* __restrict__ ts, const float* __restrict__ y0,
                const float* __restrict__ W0, const float* __restrict__ b0,
                const float* __restrict__ W1, const float* __restrict__ b1,
                const float* __restrict__ W2, const float* __restrict__ b2,
                float* __restrict__ out)
{
    __shared__ __align__(16) float sW2T[WIDTH][DATA];        // 64 KB, [k][d]
    __shared__ __align__(16) float s_y[NSAMP][DATA];
    __shared__ __align__(16) float s_yst[NSAMP][DATA];
    __shared__ __align__(16) float s_ynew[NSAMP][DATA];
    __shared__ __align__(16) float s_k[NSAMP][6][DATA];      // k1..k6
    __shared__ __align__(16) float s_h0[NSAMP][WIDTH];
    __shared__ __align__(16) float s_h1[NSAMP][WIDTH];
    __shared__ __align__(16) float s_ps0[NSAMP][2][WIDTH];
    __shared__ __align__(16) float s_ps1[NSAMP][2][WIDTH];
    __shared__ __align__(16) float s_ps2[NSAMP][8][DATA];
    __shared__ float s_b0[WIDTH], s_b1[WIDTH], s_b2[DATA];
    __shared__ float s_err[NSAMP];

    const int t  = threadIdx.x;
    const int r  = t & 255;
    const int h  = t >> 8;   // 0/1: k-half for layers 0,1; also sample id in combines
    const int d  = t & 63;
    const int kc = t >> 6;   // 0..7: k-chunk for layer 2
    const int b  = blockIdx.x;

    // ---- prologue: weights to VGPRs / LDS (one-time per block)
    float4 w0q[8], w1q[32];
    {
        const float4* p0 = reinterpret_cast<const float4*>(W0 + r * DATA + h * 32);
#pragma unroll
        for (int j = 0; j < 8; ++j) w0q[j] = p0[j];
        const float4* p1 = reinterpret_cast<const float4*>(W1 + r * WIDTH + h * 128);
#pragma unroll
        for (int j = 0; j < 32; ++j) w1q[j] = p1[j];
    }
    for (int i = t; i < WIDTH * DATA; i += NTHR) {
        const int k = i >> 6, dd = i & 63;
        sW2T[k][dd] = W2[dd * WIDTH + k];  // one-time; L2 absorbs the transpose
    }
    if (t < WIDTH) { s_b0[t] = b0[t]; s_b1[t] = b1[t]; }
    if (t < DATA)  { s_b2[t] = b2[t]; }
    if (t < NSAMP * DATA) {
        const int s = t >> 6;
        const float v = y0[(b * NSAMP + s) * DATA + d];
        s_y[s][d] = v;
        out[(size_t)(b * NSAMP + s) * TPTS * DATA + d] = v;
    }
    __syncthreads();

    // per-sample control state, replicated identically in every thread
    float dtv0 = ts[1] - ts[0];
    float dtv1 = dtv0;

    for (int iv = 0; iv < TPTS - 1; ++iv) {
        const float t1v = ts[iv + 1];
        float tc0 = ts[iv], tc1 = tc0;

        for (int ss = 0; ss < MAXSUB; ++ss) {
            const float rem0 = t1v - tc0, rem1 = t1v - tc1;
            const bool done0 = rem0 <= 1e-6f, done1 = rem1 <= 1e-6f;
            if (done0 && done1) break;  // remaining reference iters are exact identities
            const float dtc0 = done0 ? dtv0 : fminf(dtv0, rem0);
            const float dtc1 = done1 ? dtv1 : fminf(dtv1, rem1);

            // ---- stage 1
            FEVAL_CORE(&s_y[0][0], &s_y[1][0])
            if (t < 128) {
                const int s = kc;  // 0/1
                const float dtc_s = (s == 0) ? dtc0 : dtc1;
                const float kv = KV_SUM(s);
                s_k[s][0][d] = kv;
                s_yst[s][d] = s_y[s][d] + dtc_s * (A21 * kv);
            }
            __syncthreads();
            // ---- stage 2
            FEVAL_CORE(&s_yst[0][0], &s_yst[1][0])
            if (t < 128) {
                const int s = kc;
                const float dtc_s = (s == 0) ? dtc0 : dtc1;
                const float kv = KV_SUM(s);
                s_k[s][1][d] = kv;
                s_yst[s][d] = s_y[s][d] + dtc_s * (A31 * s_k[s][0][d] + A32 * kv);
            }
            __syncthreads();
            // ---- stage 3
            FEVAL_CORE(&s_yst[0][0], &s_yst[1][0])
            if (t < 128) {
                const int s = kc;
                const float dtc_s = (s == 0) ? dtc0 : dtc1;
                const float kv = KV_SUM(s);
                s_k[s][2][d] = kv;
                s_yst[s][d] = s_y[s][d] + dtc_s * (A41 * s_k[s][0][d] + A42 * s_k[s][1][d] + A43 * kv);
            }
            __syncthreads();
            // ---- stage 4
            FEVAL_CORE(&s_yst[0][0], &s_yst[1][0])
            if (t < 128) {
                const int s = kc;
                const float dtc_s = (s == 0) ? dtc0 : dtc1;
                const float kv = KV_SUM(s);
                s_k[s][3][d] = kv;
                s_yst[s][d] = s_y[s][d] + dtc_s * (A51 * s_k[s][0][d] + A52 * s_k[s][1][d]
                                                 + A53 * s_k[s][2][d] + A54 * kv);
            }
            __syncthreads();
            // ---- stage 5
            FEVAL_CORE(&s_yst[0][0], &s_yst[1][0])
            if (t < 128) {
                const int s = kc;
                const float dtc_s = (s == 0) ? dtc0 : dtc1;
                const float kv = KV_SUM(s);
                s_k[s][4][d] = kv;
                s_yst[s][d] = s_y[s][d] + dtc_s * (A61 * s_k[s][0][d] + A62 * s_k[s][1][d]
                                                 + A63 * s_k[s][2][d] + A64 * s_k[s][3][d] + A65 * kv);
            }
            __syncthreads();
            // ---- stage 6 -> y_new
            FEVAL_CORE(&s_yst[0][0], &s_yst[1][0])
            if (t < 128) {
                const int s = kc;
                const float dtc_s = (s == 0) ? dtc0 : dtc1;
                const float kv = KV_SUM(s);
                s_k[s][5][d] = kv;
                s_ynew[s][d] = s_y[s][d] + dtc_s * (B1c * s_k[s][0][d] + B2c * s_k[s][1][d]
                                                  + B3c * s_k[s][2][d] + B4c * s_k[s][3][d]
                                                  + B5c * s_k[s][4][d] + B6c * kv);
            }
            __syncthreads();
            // ---- stage 7 (error estimate only)
            FEVAL_CORE(&s_ynew[0][0], &s_ynew[1][0])
            if (t < 128) {
                const int s = kc;
                const float dtc_s = (s == 0) ? dtc0 : dtc1;
                const float kv = KV_SUM(s);  // k7
                const float e = dtc_s * (E1c * s_k[s][0][d] + E2c * s_k[s][1][d]
                                       + E3c * s_k[s][2][d] + E4c * s_k[s][3][d]
                                       + E5c * s_k[s][4][d] + E6c * s_k[s][5][d] + E7c * kv);
                const float yv = s_y[s][d], ynv = s_ynew[s][d];
                const float sc = ATOLc + RTOLc * fmaxf(fabsf(yv), fabsf(ynv));
                const float rr = e / sc;
                float v = rr * rr;
#pragma unroll
                for (int off = 32; off > 0; off >>= 1) v += __shfl_xor(v, off, 64);
                if (d == 0) s_err[s] = v;
            }
            __syncthreads();

            // ---- controller (replicated; identical in every thread)
            const float en0 = sqrtf(s_err[0] * (1.0f / DATA));
            const float en1 = sqrtf(s_err[1] * (1.0f / DATA));
            const bool acc0 = en0 <= 1.0f, acc1 = en1 <= 1.0f;
            float f0 = fminf(fmaxf(SAFETYc * powf(fmaxf(en0, 1e-10f), -0.2f), FMINc), FMAXc);
            float f1 = fminf(fmaxf(SAFETYc * powf(fmaxf(en1, 1e-10f), -0.2f), FMINc), FMAXc);
            const bool step0 = acc0 && !done0, step1 = acc1 && !done1;
            if (t < 128) {
                const int s = kc;
                const bool st = (s == 0) ? step0 : step1;
                if (st) s_y[s][d] = s_ynew[s][d];
            }
            if (step0) tc0 += dtc0;
            if (step1) tc1 += dtc1;
            dtv0 = done0 ? dtv0 : dtc0 * f0;
            dtv1 = done1 ? dtv1 : dtc1 * f1;
            __syncthreads();
        }

        if (t < 128) {
            const int s = kc;
            out[(size_t)(b * NSAMP + s) * TPTS * DATA + (size_t)(iv + 1) * DATA + d] = s_y[s][d];
        }
        // no barrier needed: next substep only reads s_y before any write to it
    }
}

extern "C" void kernel_launch(void* const* d_in, const int* in_sizes, int n_in,
                              void* d_out, int out_size, void* d_ws, size_t ws_size,
                              hipStream_t stream)
{
    const float* ts = (const float*)d_in[0];
    const float* y0 = (const float*)d_in[1];
    const float* W0 = (const float*)d_in[2];
    const float* b0 = (const float*)d_in[3];
    const float* W1 = (const float*)d_in[4];
    const float* b1 = (const float*)d_in[5];
    const float* W2 = (const float*)d_in[6];
    const float* b2 = (const float*)d_in[7];
    float* out = (float*)d_out;

    ode_kernel<<<NBLK, NTHR, 0, stream>>>(ts, y0, W0, b0, W1, b1, W2, b2, out);
}